// Round 9
// baseline (484.581 us; speedup 1.0000x reference)
//
#include <hip/hip_runtime.h>
#include <cfloat>
#include <climits>
#include <cstdint>

// Problem constants
#define B_ 8
#define C_ 128
#define N_ 4096
#define OUT_ 256
#define K_ 16
#define NC_ 24          // candidate margin for exact fp64 re-rank
#define BN_ (B_ * N_)   // 32768
#define SBIAS 200.0f    // score bias keeps packed scores positive

typedef __attribute__((ext_vector_type(8))) short s16x8;
typedef __attribute__((ext_vector_type(16))) float f32x16;

static __device__ __forceinline__ ushort f2bf(float f) {
  uint32_t u = __float_as_uint(f);
  uint32_t r = (u + 0x7fffu + ((u >> 16) & 1u)) >> 16;
  return (ushort)r;
}
static __device__ __forceinline__ float bf2f(ushort u) {
  return __uint_as_float(((uint32_t)u) << 16);
}

// ---------------------------------------------------------------------------
// K1: squared norms + transpose x -> xt (B*N, C) f32 and xb16 bf16 rows.
// ---------------------------------------------------------------------------
__global__ __launch_bounds__(256) void k_sq_xt(const float* __restrict__ x,
                                               float* __restrict__ sq,
                                               float* __restrict__ xt,
                                               ushort* __restrict__ xb16) {
  const int b = blockIdx.x >> 6;
  const int n0 = (blockIdx.x & 63) << 6;
  __shared__ float xs[C_][65];
  const float* xb = x + (size_t)b * C_ * N_;
  for (int id = threadIdx.x; id < C_ * 64; id += 256) {
    const int c = id >> 6, n = id & 63;
    xs[c][n] = xb[(size_t)c * N_ + n0 + n];
  }
  __syncthreads();
  if (threadIdx.x < 64) {
    const int n = threadIdx.x;
    float acc = 0.f;
#pragma unroll
    for (int c = 0; c < C_; ++c) { const float v = xs[c][n]; acc = fmaf(v, v, acc); }
    sq[b * N_ + n0 + n] = acc;
  }
  const int r = threadIdx.x >> 2;
  const int p = threadIdx.x & 3;
  float* dst = xt + ((size_t)(b * N_ + n0 + r)) * C_ + p * 32;
#pragma unroll
  for (int c0 = 0; c0 < 32; c0 += 4) {
    float4 o;
    o.x = xs[p * 32 + c0 + 0][r];
    o.y = xs[p * 32 + c0 + 1][r];
    o.z = xs[p * 32 + c0 + 2][r];
    o.w = xs[p * 32 + c0 + 3][r];
    *(float4*)(dst + c0) = o;
  }
  ushort* bdst = xb16 + ((size_t)(b * N_ + n0 + r)) * C_ + p * 32;
#pragma unroll
  for (int c0 = 0; c0 < 32; c0 += 8) {
    s16x8 o;
#pragma unroll
    for (int e = 0; e < 8; ++e) o[e] = (short)f2bf(xs[p * 32 + c0 + e][r]);
    *(s16x8*)(bdst + c0) = o;
  }
}

// ---------------------------------------------------------------------------
// K1b: weights fp32 -> bf16.
// ---------------------------------------------------------------------------
__global__ __launch_bounds__(256) void k_wprep(const float* __restrict__ w,
                                               ushort* __restrict__ wb16) {
  const int i = blockIdx.x * 256 + threadIdx.x;   // grid 128 -> 32768
  wb16[i] = f2bf(w[i]);
}

// ---------------------------------------------------------------------------
// K2: bf16 MFMA score GEMM + branchless packed top-16 selection.
// Round-8 restructure FOR OCCUPANCY ONLY (selection logic byte-identical):
// block = 32 i-rows (grid 1024 -> 4 blocks/CU, 16 waves/CU); each of the 4
// waves scans a j-QUARTER (1024 j). Per row: 8 sorted-16 sublists (each
// top-16 of a disjoint 512-j subset -> deterministic safety: any true
// top-16 member has <=15 better scores globally). Merge: bitonic-64 sort of
// lists 0-3 (desc) and lists 4-7 (asc), elementwise max = bitonic top-64,
// 6-stage cleanup -> top-24 candidates.
// ---------------------------------------------------------------------------
__global__ __launch_bounds__(256, 4) void k_knn_mfma(
    const ushort* __restrict__ xb16, const float* __restrict__ sq,
    int* __restrict__ cand) {
  const int b  = blockIdx.x >> 7;            // 8 batches x 128 row-blocks
  const int i0 = (blockIdx.x & 127) << 5;    // 32-row block
  const int t  = threadIdx.x;
  const int w  = t >> 6;                     // wave = j-quarter 0..3
  const int lane = t & 63;
  const int kh = lane >> 5;                  // j-subclass within quarter

  __shared__ unsigned lds_lists[32 * 128];   // [row 32][list 8][slot 16] 16KB

  const ushort* xbB = xb16 + (((size_t)b) << 12) * C_;
  const float* sqB = sq + (b << 12);
  const int jq0 = w << 10;                   // wave's 1024-j quarter

  // B-fragments (X_i): lane l -> col i = i0+(l&31), k = (l>>5)*8+e
  s16x8 bfr[8];
  {
    const ushort* ip = xbB + ((size_t)(i0 + (lane & 31))) * C_ + (lane >> 5) * 8;
#pragma unroll
    for (int ks = 0; ks < 8; ++ks) bfr[ks] = *(const s16x8*)(ip + ks * 16);
  }

  unsigned lst[K_];
#pragma unroll
  for (int m = 0; m < K_; ++m) lst[m] = 0u;

  const ushort* aplane = xbB + (size_t)(lane & 31) * C_ + (lane >> 5) * 8;
  const float* sqlane = sqB + 4 * (lane >> 5);
  const unsigned vb2 = 4095u - 4u * (unsigned)(lane >> 5);

  s16x8 afA[8], afB[8];
  float4 sqA[4], sqB4[4];

#define LOADT(AF, SQ, J0)                                                  \
  {                                                                        \
    const ushort* ap = aplane + (size_t)(J0) * C_;                         \
    _Pragma("unroll")                                                      \
    for (int ks = 0; ks < 8; ++ks) (AF)[ks] = *(const s16x8*)(ap + ks * 16); \
    _Pragma("unroll")                                                      \
    for (int u = 0; u < 4; ++u) (SQ)[u] = *(const float4*)(sqlane + (J0) + 8 * u); \
  }

#define COMPT(AF, SQ, J0)                                                  \
  {                                                                        \
    f32x16 acc;                                                            \
    _Pragma("unroll")                                                      \
    for (int r = 0; r < 16; ++r) {                                         \
      const float sv = (r & 1) ? ((r & 2) ? (SQ)[r >> 2].w : (SQ)[r >> 2].y) \
                               : ((r & 2) ? (SQ)[r >> 2].z : (SQ)[r >> 2].x); \
      acc[r] = fmaf(sv, -0.5f, SBIAS);                                     \
    }                                                                      \
    acc = __builtin_amdgcn_mfma_f32_32x32x16_bf16((AF)[0], bfr[0], acc, 0, 0, 0); \
    _Pragma("unroll")                                                      \
    for (int ks = 1; ks < 8; ++ks)                                         \
      acc = __builtin_amdgcn_mfma_f32_32x32x16_bf16((AF)[ks], bfr[ks], acc, 0, 0, 0); \
    _Pragma("unroll")                                                      \
    for (int r = 0; r < 16; ++r) {                                         \
      const unsigned u = __float_as_uint(acc[r]);                          \
      unsigned p = (u & 0xFFFFF000u) | (vb2 - (unsigned)((J0) + (r & 3) + 8 * (r >> 2))); \
      _Pragma("unroll")                                                    \
      for (int m = 0; m < K_; ++m) {                                       \
        const unsigned mx = p > lst[m] ? p : lst[m];                       \
        const unsigned mn = p > lst[m] ? lst[m] : p;                       \
        lst[m] = mx; p = mn;                                               \
      }                                                                    \
    }                                                                      \
  }

  LOADT(afA, sqA, jq0);
  for (int jt = 0; jt < 32; jt += 2) {
    const int j0e = jq0 + jt * 32;
    LOADT(afB, sqB4, j0e + 32);
    COMPT(afA, sqA, j0e);
    if (jt + 2 < 32) LOADT(afA, sqA, j0e + 64);
    COMPT(afB, sqB4, j0e + 32);
  }

  // ---- write 8 sublists per row to LDS, merge -> top-24 candidates ----
  {
    const int rl = lane & 31;
    const int listid = (w << 1) + kh;        // 0..7
    unsigned* dst = &lds_lists[(rl * 8 + listid) * 16];
#pragma unroll
    for (int m = 0; m < K_; ++m) dst[m] = lst[m];
  }
  __syncthreads();

  const int up = lane >> 5;
  const int ladj = up ? (lane ^ 31) : lane;
  const int run = lane >> 4;
  const int slot = (run & 1) ? (15 - (lane & 15)) : (lane & 15);
  for (int rr = 0; rr < 8; ++rr) {
    const int row = (w << 3) + rr;
    const unsigned* base = &lds_lists[row * 128];
    unsigned vA = base[run * 16 + slot];        // lists 0-3
    unsigned vB = base[64 + run * 16 + slot];   // lists 4-7
    // group A: stage A (pairs of sorted-16 -> 32-bitonic halves)
#pragma unroll
    for (int ms = 16; ms >= 1; ms >>= 1) {
      const unsigned pv = __shfl_xor(vA, ms, 64);
      const unsigned mx = vA > pv ? vA : pv;
      const unsigned mn = vA > pv ? pv : vA;
      vA = ((ladj & ms) == 0) ? mx : mn;
    }
    // group A: stage B -> sorted DESC across 64 lanes
#pragma unroll
    for (int ms = 32; ms >= 1; ms >>= 1) {
      const unsigned pv = __shfl_xor(vA, ms, 64);
      const unsigned mx = vA > pv ? vA : pv;
      const unsigned mn = vA > pv ? pv : vA;
      vA = ((lane & ms) == 0) ? mx : mn;
    }
    // group B: stage A
#pragma unroll
    for (int ms = 16; ms >= 1; ms >>= 1) {
      const unsigned pv = __shfl_xor(vB, ms, 64);
      const unsigned mx = vB > pv ? vB : pv;
      const unsigned mn = vB > pv ? pv : vB;
      vB = ((ladj & ms) == 0) ? mx : mn;
    }
    // group B: stage B with inverted direction -> sorted ASC across lanes
#pragma unroll
    for (int ms = 32; ms >= 1; ms >>= 1) {
      const unsigned pv = __shfl_xor(vB, ms, 64);
      const unsigned mx = vB > pv ? vB : pv;
      const unsigned mn = vB > pv ? pv : vB;
      vB = ((lane & ms) != 0) ? mx : mn;
    }
    // merge two sorted-64 (desc x asc): elementwise max = bitonic top-64
    unsigned v = vA > vB ? vA : vB;
#pragma unroll
    for (int ms = 32; ms >= 1; ms >>= 1) {
      const unsigned pv = __shfl_xor(v, ms, 64);
      const unsigned mx = v > pv ? v : pv;
      const unsigned mn = v > pv ? pv : v;
      v = ((lane & ms) == 0) ? mx : mn;
    }
    if (lane < NC_) {
      const int j = 4095 - (int)(v & 0xFFFu);
      cand[((size_t)((b << 12) + i0 + row)) * NC_ + lane] = j;
    }
  }
}

// ---------------------------------------------------------------------------
// K3: exact fp64 re-rank of 24 candidates -> top-16, fused gather+max-pool,
// emits pooled bf16 rows. Half-wave (32 lanes) per point row.
// ---------------------------------------------------------------------------
__global__ __launch_bounds__(256) void k_refine_gather(
    const float* __restrict__ xt, const int* __restrict__ cand,
    ushort* __restrict__ pooled16) {
  const int half = threadIdx.x >> 5;
  const int l = threadIdx.x & 31;
  const int row = blockIdx.x * 8 + half;
  const int b = row >> 12;
  const size_t bbase = (size_t)(b << 12);
  const float4* xr4 = (const float4*)(xt + (size_t)row * C_);
  double d = DBL_MAX;
  int j = INT_MAX;
  if (l < NC_) {
    j = cand[(size_t)row * NC_ + l];
    const float4* xj4 = (const float4*)(xt + (bbase + j) * C_);
    double acc = 0.0;
#pragma unroll 8
    for (int c = 0; c < C_ / 4; ++c) {
      const float4 a = xr4[c];
      const float4 v = xj4[c];
      const double dx = (double)a.x - (double)v.x;
      const double dy = (double)a.y - (double)v.y;
      const double dz = (double)a.z - (double)v.z;
      const double dw = (double)a.w - (double)v.w;
      acc += dx * dx + dy * dy + dz * dz + dw * dw;
    }
    d = acc;
  }
  int win[K_];
#pragma unroll
  for (int m = 0; m < K_; ++m) {
    double bd = d; int bj = j;
#pragma unroll
    for (int off = 16; off > 0; off >>= 1) {
      const double od = __shfl_xor(bd, off, 32);
      const int oj = __shfl_xor(bj, off, 32);
      if (od < bd || (od == bd && oj < bj)) { bd = od; bj = oj; }
    }
    win[m] = bj;
    if (bj == j) d = DBL_MAX;
  }
  const int c0 = l * 4;
  float4 mx = make_float4(-FLT_MAX, -FLT_MAX, -FLT_MAX, -FLT_MAX);
#pragma unroll
  for (int m = 0; m < K_; ++m) {
    const float4 v = *(const float4*)(xt + (bbase + win[m]) * C_ + c0);
    mx.x = fmaxf(mx.x, v.x);
    mx.y = fmaxf(mx.y, v.y);
    mx.z = fmaxf(mx.z, v.z);
    mx.w = fmaxf(mx.w, v.w);
  }
  ushort4 o;
  o.x = f2bf(mx.x); o.y = f2bf(mx.y); o.z = f2bf(mx.z); o.w = f2bf(mx.w);
  *(ushort4*)(pooled16 + (size_t)row * C_ + c0) = o;
}

// ---------------------------------------------------------------------------
// K4: bf16 MFMA conv + bias -> y bf16, layout (B,OUT,N).
// ---------------------------------------------------------------------------
__global__ __launch_bounds__(256) void k_conv_y(const ushort* __restrict__ pooled16,
                                                const ushort* __restrict__ wb16,
                                                const float* __restrict__ bias,
                                                ushort* __restrict__ y16) {
  const int i0 = blockIdx.x << 7;
  const int b = i0 >> 12;
  const int nb = i0 & (N_ - 1);
  const int t = threadIdx.x, w = t >> 6, l = t & 63;
  __shared__ float biasl[OUT_];
  biasl[t] = bias[t];
  __syncthreads();
  const int kh = l >> 5;
  const int irow = i0 + (w << 5) + (l & 31);
  s16x8 pf[8];
  {
    const ushort* pp = pooled16 + (size_t)irow * C_ + kh * 8;
#pragma unroll
    for (int ks = 0; ks < 8; ++ks) pf[ks] = *(const s16x8*)(pp + ks * 16);
  }
  const int nout = nb + (w << 5) + (l & 31);
  for (int ot = 0; ot < 8; ++ot) {
    const ushort* wp = wb16 + (size_t)(ot * 32 + (l & 31)) * C_ + kh * 8;
    s16x8 wf[8];
#pragma unroll
    for (int ks = 0; ks < 8; ++ks) wf[ks] = *(const s16x8*)(wp + ks * 16);
    f32x16 acc;
#pragma unroll
    for (int r = 0; r < 16; ++r) acc[r] = 0.f;
#pragma unroll
    for (int ks = 0; ks < 8; ++ks)
      acc = __builtin_amdgcn_mfma_f32_32x32x16_bf16(wf[ks], pf[ks], acc, 0, 0, 0);
#pragma unroll
    for (int r = 0; r < 16; ++r) {
      const int o = ot * 32 + (r & 3) + 8 * (r >> 2) + 4 * kh;
      const float y = acc[r] + biasl[o];
      y16[((size_t)(b * OUT_ + o) << 12) + nout] = f2bf(y);
    }
  }
}

// ---------------------------------------------------------------------------
// K5: per-channel BN stats from the STORED y (self-consistent by design).
// ---------------------------------------------------------------------------
__global__ __launch_bounds__(256) void k_ystats(const ushort* __restrict__ y16,
                                                const float* __restrict__ gamma,
                                                const float* __restrict__ beta,
                                                float2* __restrict__ ss) {
  const int o = blockIdx.x;
  const int t = threadIdx.x;
  float s1 = 0.f, s2 = 0.f;
  for (int b = 0; b < B_; ++b) {
    const ushort* yp = y16 + ((size_t)(b * OUT_ + o) << 12);
#pragma unroll
    for (int it = 0; it < 2; ++it) {
      const s16x8 v = *(const s16x8*)(yp + (it * 256 + t) * 8);
#pragma unroll
      for (int e = 0; e < 8; ++e) {
        const float f = bf2f((ushort)v[e]);
        s1 += f;
        s2 = fmaf(f, f, s2);
      }
    }
  }
#pragma unroll
  for (int off = 32; off > 0; off >>= 1) {
    s1 += __shfl_xor(s1, off, 64);
    s2 += __shfl_xor(s2, off, 64);
  }
  __shared__ float r1[4], r2[4];
  if ((t & 63) == 0) { r1[t >> 6] = s1; r2[t >> 6] = s2; }
  __syncthreads();
  if (t == 0) {
    const float S1 = r1[0] + r1[1] + r1[2] + r1[3];
    const float S2 = r2[0] + r2[1] + r2[2] + r2[3];
    const float inv = 1.f / (float)BN_;
    const float mean = S1 * inv;
    const float var = S2 * inv - mean * mean;
    const float scale = gamma[o] / sqrtf(var + 1e-5f);
    float2 r; r.x = scale; r.y = beta[o] - mean * scale;
    ss[o] = r;
  }
}

// ---------------------------------------------------------------------------
// K6: elementwise BN apply + ReLU: out = max(y*scale + shift, 0), fp32 out.
// ---------------------------------------------------------------------------
__global__ __launch_bounds__(256) void k_bn(const ushort* __restrict__ y16,
                                            const float2* __restrict__ ss,
                                            float* __restrict__ out) {
  const size_t idx = ((size_t)blockIdx.x * 256 + threadIdx.x) * 4;
  const int o = (int)((idx >> 12) & (OUT_ - 1));
  const float2 sv = ss[o];
  const ushort4 v = *(const ushort4*)(y16 + idx);
  float4 r;
  r.x = fmaxf(fmaf(bf2f(v.x), sv.x, sv.y), 0.f);
  r.y = fmaxf(fmaf(bf2f(v.y), sv.x, sv.y), 0.f);
  r.z = fmaxf(fmaf(bf2f(v.z), sv.x, sv.y), 0.f);
  r.w = fmaxf(fmaf(bf2f(v.w), sv.x, sv.y), 0.f);
  *(float4*)(out + idx) = r;
}

// ---------------------------------------------------------------------------
// Launcher. ws layout:
//   sq f32[32768] | xt f32[4194304] (aliased by y16 bf16[8388608] after K3)
//   | cand i32[786432] | pooled16 u16[4194304] | xb16 u16[4194304]
//   | wb16 u16[32768] | ss float2[256]       total ≈ 35.4 MB
// ---------------------------------------------------------------------------
extern "C" void kernel_launch(void* const* d_in, const int* in_sizes, int n_in,
                              void* d_out, int out_size, void* d_ws, size_t ws_size,
                              hipStream_t stream) {
  const float* x      = (const float*)d_in[0];
  const float* conv_w = (const float*)d_in[1];
  const float* conv_b = (const float*)d_in[2];
  const float* gamma  = (const float*)d_in[3];
  const float* beta   = (const float*)d_in[4];
  float* out = (float*)d_out;

  float* ws = (float*)d_ws;
  float* sq = ws;                                           // 32768 f32
  float* xt = sq + BN_;                                     // 4194304 f32
  ushort* y16 = (ushort*)xt;                                // alias: 8388608 bf16 (exact fit)
  int*   cand = (int*)(xt + (size_t)BN_ * C_);              // 786432 i32
  ushort* pooled16 = (ushort*)(cand + (size_t)BN_ * NC_);   // 4194304 u16
  ushort* xb16 = pooled16 + (size_t)BN_ * C_;               // 4194304 u16
  ushort* wb16 = xb16 + (size_t)BN_ * C_;                   // 32768 u16
  float2* ss = (float2*)(wb16 + (size_t)OUT_ * C_);         // 256 float2

  k_sq_xt<<<B_ * (N_ / 64), 256, 0, stream>>>(x, sq, xt, xb16);
  k_wprep<<<(OUT_ * C_) / 256, 256, 0, stream>>>(conv_w, wb16);
  k_knn_mfma<<<B_ * (N_ / 32), 256, 0, stream>>>(xb16, sq, cand);
  k_refine_gather<<<BN_ / 8, 256, 0, stream>>>(xt, cand, pooled16);
  k_conv_y<<<BN_ / 128, 256, 0, stream>>>(pooled16, wb16, conv_b, y16);
  k_ystats<<<OUT_, 256, 0, stream>>>(y16, gamma, beta, ss);
  k_bn<<<(BN_ * OUT_ / 4) / 256, 256, 0, stream>>>(y16, ss, out);
}